// Round 7
// baseline (184.974 us; speedup 1.0000x reference)
//
#include <hip/hip_runtime.h>
#include <hip/hip_bf16.h>
#include <math.h>

#define B_   8
#define T_   96
#define N_   1024
#define C_   64
#define H_   64
#define BT_  768
#define EMB_ 8

typedef __attribute__((ext_vector_type(8))) short short8v;
typedef __attribute__((ext_vector_type(4))) float f32x4;

__device__ __forceinline__ ushort f2bf(float f) {   // RNE bf16
    unsigned int u = __float_as_uint(f);
    unsigned int r = (u + 0x7fffu + ((u >> 16) & 1u)) >> 16;
    return (ushort)r;
}
__device__ __forceinline__ float bf2f(ushort h) {
    return __uint_as_float(((unsigned int)h) << 16);
}

// ---------------------------------------------------------------------------
// k_setup: block 0 = wp1/wpb; block 1 = w1 -> MFMA-A-frag bf16; block 2 = w2
// -> MFMA-B-frag bf16; blocks 3..1026 = adj row sums; blocks 1027..1218 =
// x transpose tiles (64x64) -> xT[n][bt].
// ---------------------------------------------------------------------------
__global__ __launch_bounds__(256) void k_setup(const float* __restrict__ wpool,
                                               const float* __restrict__ w_in,
                                               const float* __restrict__ b_in,
                                               const float* __restrict__ adj,
                                               const float* __restrict__ w1,
                                               const float* __restrict__ w2,
                                               const float* __restrict__ x,
                                               float* __restrict__ wp1,
                                               float* __restrict__ wpb,
                                               float* __restrict__ rs,
                                               ushort* __restrict__ wfrag1,
                                               ushort* __restrict__ wfrag2,
                                               float* __restrict__ xT) {
    int bid = blockIdx.x;
    int tid = threadIdx.x;
    if (bid == 0) {
        for (int e = tid; e < EMB_ * C_; e += 256) {
            int d = e >> 6, c = e & 63;
            float s1 = 0.f, s2 = 0.f;
            for (int i = 0; i < C_; ++i) {
                float w = wpool[(d * C_ + i) * C_ + c];
                s1 += w_in[i] * w;
                s2 += b_in[i] * w;
            }
            wp1[e] = s1;
            wpb[e] = s2;
        }
    } else if (bid == 1) {
        for (int e = tid; e < 6144; e += 256) {
            int j = e & 7, lane = (e >> 3) & 63, frag = e >> 9;
            int mt = frag / 3, k0 = frag - 3 * mt;
            int h = 16 * mt + (lane & 15);
            int t = 32 * k0 + 8 * (lane >> 4) + j;
            wfrag1[e] = f2bf(w1[h * T_ + t]);
        }
    } else if (bid == 2) {
        for (int e = tid; e < 6144; e += 256) {
            int j = e & 7, lane = (e >> 3) & 63, frag = e >> 9;
            int mt2 = frag >> 1, ks = frag & 1;
            int t = 16 * mt2 + (lane & 15);
            int h = 32 * ks + 8 * (lane >> 4) + j;
            wfrag2[e] = f2bf(w2[t * H_ + h]);
        }
    } else if (bid < 1027) {
        int row = bid - 3;
        float s = 0.f;
        for (int m = tid; m < N_; m += 256) s += adj[row * N_ + m];
#pragma unroll
        for (int off = 32; off; off >>= 1) s += __shfl_down(s, off);
        __shared__ float red[4];
        if ((tid & 63) == 0) red[tid >> 6] = s;
        __syncthreads();
        if (tid == 0) rs[row] = red[0] + red[1] + red[2] + red[3];
    } else {
        // transpose x[768][1024] -> xT[1024][768], 64x64 tiles
        __shared__ float tile[64][65];
        int tnum = bid - 1027;          // 0..191
        int ti = tnum >> 4;             // 0..11  (bt tiles)
        int tj = tnum & 15;             // 0..15  (n tiles)
#pragma unroll
        for (int k = 0; k < 16; ++k) {
            int idx = tid + 256 * k;    // 0..4095
            int r = idx >> 6, cq = idx & 63;
            tile[r][cq] = x[(ti * 64 + r) * N_ + tj * 64 + cq];
        }
        __syncthreads();
#pragma unroll
        for (int k = 0; k < 16; ++k) {
            int idx = tid + 256 * k;
            int r = idx >> 6, cq = idx & 63;
            xT[(tj * 64 + r) * BT_ + ti * 64 + cq] = tile[cq][r];
        }
    }
}

// ---------------------------------------------------------------------------
// k_tab: 1 block. waves 0..2 (ty): WT/BT[3][64] + per-(ty,group) sums TAB[3][4][9]
// wave 3: GG[4][5]
// ---------------------------------------------------------------------------
__global__ __launch_bounds__(256) void k_tab(const float* __restrict__ wp1,
                                             const float* __restrict__ wpb,
                                             const float* __restrict__ emb,
                                             const float* __restrict__ w_in,
                                             const float* __restrict__ b_in,
                                             float* __restrict__ WT,
                                             float* __restrict__ BTb,
                                             float* __restrict__ TAB,
                                             float* __restrict__ GG) {
    int tid = threadIdx.x;
    int wave = tid >> 6, lane = tid & 63;
    int lq = lane & 15, g = lane >> 4;
    if (wave < 3) {
        int ty = wave, c = lane;
        float w = 0.f, bb = 0.f;
#pragma unroll
        for (int d = 0; d < EMB_; ++d) {
            float ev = emb[ty * EMB_ + d];
            w += ev * wp1[d * C_ + c];
            bb += ev * wpb[d * C_ + c];
        }
        WT[ty * C_ + c] = w;
        BTb[ty * C_ + c] = bb;
        float wi = w_in[c], bi = b_in[c];
        float vals[9] = {w, bb, w * w, bb * bb, w * wi, w * bi, wi * bb, bb * bi, w * bb};
#pragma unroll
        for (int q = 0; q < 9; ++q) {
            vals[q] += __shfl_xor(vals[q], 1);
            vals[q] += __shfl_xor(vals[q], 2);
            vals[q] += __shfl_xor(vals[q], 4);
            vals[q] += __shfl_xor(vals[q], 8);
        }
        if (lq == 0) {
#pragma unroll
            for (int q = 0; q < 9; ++q) TAB[(ty * 4 + g) * 9 + q] = vals[q];
        }
    } else {
        int c = lane;
        float wi = w_in[c], bi = b_in[c];
        float v5[5] = {wi, bi, wi * wi, bi * bi, wi * bi};
#pragma unroll
        for (int q = 0; q < 5; ++q) {
            v5[q] += __shfl_xor(v5[q], 1);
            v5[q] += __shfl_xor(v5[q], 2);
            v5[q] += __shfl_xor(v5[q], 4);
            v5[q] += __shfl_xor(v5[q], 8);
        }
        if (lq == 0) {
#pragma unroll
            for (int q = 0; q < 5; ++q) GG[g * 5 + q] = v5[q];
        }
    }
}

// ---------------------------------------------------------------------------
// k_ax (bf16 MFMA): ax[bt][n] (row-major for k_gn) + axT[n][bt] (for k_main)
// ---------------------------------------------------------------------------
__global__ __launch_bounds__(256, 4) void k_ax(const float* __restrict__ x,
                                               const float* __restrict__ adj,
                                               float* __restrict__ axo,
                                               float* __restrict__ axT) {
    __shared__ ushort Xs[32 * 64];
    __shared__ ushort As[32 * 64];
    const int tid = threadIdx.x;
    const int wave = tid >> 6, lane = tid & 63;
    const int lq = lane & 15, g4 = lane >> 4;
    const int n0 = blockIdx.x * 32, m0 = blockIdx.y * 32;
    const int mi = wave >> 1, ni = wave & 1;
    const int sr = tid >> 3, sq = tid & 7;
    const int sqx = sq ^ (sr & 7);
    const int ra = 16 * mi + lq, rb = 16 * ni + lq;

    f32x4 acc = {0.f, 0.f, 0.f, 0.f};

    for (int k0 = 0; k0 < N_; k0 += 64) {
        __syncthreads();
        {
            const float* px = x + (m0 + sr) * N_ + k0 + sq * 8;
            float4 xa = *(const float4*)px;
            float4 xb = *(const float4*)(px + 4);
            union { short8v v; __hip_bfloat162 h[4]; } o;
            o.h[0] = __float22bfloat162_rn(make_float2(xa.x, xa.y));
            o.h[1] = __float22bfloat162_rn(make_float2(xa.z, xa.w));
            o.h[2] = __float22bfloat162_rn(make_float2(xb.x, xb.y));
            o.h[3] = __float22bfloat162_rn(make_float2(xb.z, xb.w));
            *(short8v*)&Xs[sr * 64 + sqx * 8] = o.v;

            const float* pa = adj + (n0 + sr) * N_ + k0 + sq * 8;
            float4 aa = *(const float4*)pa;
            float4 ab = *(const float4*)(pa + 4);
            o.h[0] = __float22bfloat162_rn(make_float2(aa.x, aa.y));
            o.h[1] = __float22bfloat162_rn(make_float2(aa.z, aa.w));
            o.h[2] = __float22bfloat162_rn(make_float2(ab.x, ab.y));
            o.h[3] = __float22bfloat162_rn(make_float2(ab.z, ab.w));
            *(short8v*)&As[sr * 64 + sqx * 8] = o.v;
        }
        __syncthreads();
#pragma unroll
        for (int ks = 0; ks < 2; ++ks) {
            short8v a = *(const short8v*)&Xs[ra * 64 + ((4 * ks + g4) ^ (ra & 7)) * 8];
            short8v bb = *(const short8v*)&As[rb * 64 + ((4 * ks + g4) ^ (rb & 7)) * 8];
            acc = __builtin_amdgcn_mfma_f32_16x16x32_bf16(a, bb, acc, 0, 0, 0);
        }
    }
#pragma unroll
    for (int r = 0; r < 4; ++r)
        axo[(m0 + 16 * mi + 4 * g4 + r) * N_ + n0 + 16 * ni + lq] = acc[r];
    // transposed copy: contiguous float4 along bt
    float4 tv = make_float4(acc[0], acc[1], acc[2], acc[3]);
    *(float4*)&axT[(n0 + 16 * ni + lq) * BT_ + m0 + 16 * mi + 4 * g4] = tv;
}

// ---------------------------------------------------------------------------
// k_gn v2: per bt, per-type feature sums -> mu/rsig via TAB/GG contraction.
// ---------------------------------------------------------------------------
__global__ __launch_bounds__(256) void k_gn(const float* __restrict__ x,
                                            const float* __restrict__ ax,
                                            const float* __restrict__ rs,
                                            const int* __restrict__ ntype,
                                            const float* __restrict__ TAB,
                                            const float* __restrict__ GG,
                                            float* __restrict__ muT,
                                            float* __restrict__ rgT) {
    int bt = blockIdx.x;
    int tid = threadIdx.x;
    const float* axr = ax + bt * N_;
    const float* xr = x + bt * N_;
    float S[23];
#pragma unroll
    for (int q = 0; q < 23; ++q) S[q] = 0.f;
#pragma unroll
    for (int i = 0; i < 4; ++i) {
        int n = tid + 256 * i;
        float a = axr[n], xv = xr[n], r = rs[n];
        int ty = ntype[n];
        float e0 = (ty == 0) ? 1.f : 0.f;
        float e1 = (ty == 1) ? 1.f : 0.f;
        float e2 = (ty == 2) ? 1.f : 0.f;
        float a2 = a * a, axp = a * xv, ar = a * r, xrr = xv * r, r2 = r * r;
        S[0] += e0 * a;   S[1] += e1 * a;   S[2] += e2 * a;
        S[3] += e0 * r;   S[4] += e1 * r;   S[5] += e2 * r;
        S[6] += e0 * a2;  S[7] += e1 * a2;  S[8] += e2 * a2;
        S[9] += e0 * r2;  S[10] += e1 * r2; S[11] += e2 * r2;
        S[12] += e0 * axp; S[13] += e1 * axp; S[14] += e2 * axp;
        S[15] += e0 * ar; S[16] += e1 * ar; S[17] += e2 * ar;
        S[18] += e0 * xrr; S[19] += e1 * xrr; S[20] += e2 * xrr;
        S[21] += xv;      S[22] += xv * xv;
    }
#pragma unroll
    for (int q = 0; q < 23; ++q) {
#pragma unroll
        for (int off = 32; off; off >>= 1) S[q] += __shfl_down(S[q], off);
    }
    __shared__ float wred[4][23];
    __shared__ float tot[23];
    int wave = tid >> 6, lane = tid & 63;
    if (lane == 0) {
#pragma unroll
        for (int q = 0; q < 23; ++q) wred[wave][q] = S[q];
    }
    __syncthreads();
    if (tid < 23) tot[tid] = wred[0][tid] + wred[1][tid] + wred[2][tid] + wred[3][tid];
    __syncthreads();
    if (tid < 4) {
        int g = tid;
        float M = 0.f, Q = 0.f;
#pragma unroll
        for (int ty = 0; ty < 3; ++ty) {
            const float* tb = TAB + (ty * 4 + g) * 9;
            float A1v = tot[0 + ty], R1v = tot[3 + ty], A2v = tot[6 + ty];
            float R2v = tot[9 + ty], AXv = tot[12 + ty], ARv = tot[15 + ty];
            float XRv = tot[18 + ty];
            M += tb[0] * A1v + tb[1] * R1v;
            Q += tb[2] * A2v + tb[3] * R2v +
                 2.f * (tb[4] * AXv + tb[5] * A1v + tb[6] * XRv + tb[7] * R1v + tb[8] * ARv);
        }
        float Sx = tot[21], Sx2 = tot[22];
        const float* gg = GG + g * 5;
        M += gg[0] * Sx + 1024.f * gg[1];
        Q += gg[2] * Sx2 + 2.f * gg[4] * Sx + 1024.f * gg[3];
        const float inv = 1.f / 16384.f;
        float m = M * inv;
        float v = Q * inv - m * m;
        int b = bt / T_, t = bt - b * T_;
        muT[(b * 4 + g) * T_ + t] = m;
        rgT[(b * 4 + g) * T_ + t] = rsqrtf(v + 1e-5f);
    }
}

// ---------------------------------------------------------------------------
// k_main v5: 4 nodes per block, grid (256, 8), 256 threads. Weight frags in
// VGPRs amortized over 4 n. Coalesced xT/axT staging. No barriers in n-loop
// (Hs/Hd rows wave-private). Output float4 per t row.
// ---------------------------------------------------------------------------
__global__ __launch_bounds__(256, 4) void k_main(const float* __restrict__ xT,
                                                 const float* __restrict__ axT,
                                                 const float* __restrict__ rs,
                                                 const int* __restrict__ ntype,
                                                 const float* __restrict__ WT,
                                                 const float* __restrict__ BTb,
                                                 const float* __restrict__ muT,
                                                 const float* __restrict__ rgT,
                                                 const float* __restrict__ w_in,
                                                 const float* __restrict__ b_in,
                                                 const float* __restrict__ gn_w,
                                                 const float* __restrict__ gn_b,
                                                 const ushort* __restrict__ wfrag1,
                                                 const ushort* __restrict__ wfrag2,
                                                 const float* __restrict__ b1,
                                                 const float* __restrict__ b2,
                                                 const float* __restrict__ w_out,
                                                 const float* __restrict__ b_out,
                                                 float* __restrict__ out) {
    __shared__ ushort Hs[64 * 104];
    __shared__ ushort Hd[64 * 104];
    __shared__ float axs[4][96], xs[4][96];
    __shared__ float musT[4 * 100], rgsT[4 * 100];
    __shared__ float redp[4][96][4];

    const int tid = threadIdx.x;
    const int n0 = blockIdx.x * 4;
    const int b = blockIdx.y;
    const int wm = tid >> 6;
    const int lane = tid & 63;
    const int lq = lane & 15;
    const int g4 = lane >> 4;

    // ---- weight fragments -> VGPRs (24 x global b128, L2-resident) ----
    short8v w1f[4][3], w2f[6][2];
#pragma unroll
    for (int mt = 0; mt < 4; ++mt)
#pragma unroll
        for (int k0 = 0; k0 < 3; ++k0)
            w1f[mt][k0] = *(const short8v*)(wfrag1 + (((mt * 3 + k0) << 6) + lane) * 8);
#pragma unroll
    for (int mt2 = 0; mt2 < 6; ++mt2)
#pragma unroll
        for (int ks = 0; ks < 2; ++ks)
            w2f[mt2][ks] = *(const short8v*)(wfrag2 + (((mt2 * 2 + ks) << 6) + lane) * 8);

    // ---- coalesced staging: 4 ax columns + 4 x columns (96 floats each) ----
    for (int j = tid; j < 384; j += 256) {
        int nn = j / 96, t = j - nn * 96;
        axs[nn][t] = axT[(n0 + nn) * BT_ + b * T_ + t];
        xs[nn][t] = xT[(n0 + nn) * BT_ + b * T_ + t];
    }
    for (int j = tid; j < 384; j += 256) {
        int g = j / 96, t = j - 96 * g;
        musT[g * 100 + t] = muT[b * 384 + j];
        rgsT[g * 100 + t] = rgT[b * 384 + j];
    }

    // ---- per-c constants (hoisted across the n-loop) ----
    const int c = 16 * wm + lq;
    const float wic = w_in[c], bic = b_in[c];
    const float gwc = gn_w[c], gbc = gn_b[c];
    const float wlcA[3] = {WT[c], WT[64 + c], WT[128 + c]};
    const float blcA[3] = {BTb[c], BTb[64 + c], BTb[128 + c]};
    float4 b1q[4];
#pragma unroll
    for (int mt = 0; mt < 4; ++mt) b1q[mt] = *(const float4*)&b1[16 * mt + 4 * g4];
    float b2q[6];
#pragma unroll
    for (int mt2 = 0; mt2 < 6; ++mt2) b2q[mt2] = b2[16 * mt2 + lq];
    const float4 wo4 = *(const float4*)&w_out[16 * wm + 4 * g4];
    __syncthreads();

    // ================= n-loop (no internal barriers) =================
#pragma unroll 1
    for (int nn = 0; nn < 4; ++nn) {
        const int n = n0 + nn;
        const int ty = ntype[n];
        const float wlc = (ty == 0) ? wlcA[0] : (ty == 1) ? wlcA[1] : wlcA[2];
        const float blc = (ty == 0) ? blcA[0] : (ty == 1) ? blcA[1] : blcA[2];
        const float base = rs[n] * blc + bic;

        f32x4 acc1[4] = {{0.f, 0.f, 0.f, 0.f}, {0.f, 0.f, 0.f, 0.f},
                         {0.f, 0.f, 0.f, 0.f}, {0.f, 0.f, 0.f, 0.f}};
#pragma unroll
        for (int k0 = 0; k0 < 3; ++k0) {
            int t8 = 32 * k0 + 8 * g4;
            float4 a0 = *(const float4*)&axs[nn][t8];
            float4 a1 = *(const float4*)&axs[nn][t8 + 4];
            float4 x0 = *(const float4*)&xs[nn][t8];
            float4 x1 = *(const float4*)&xs[nn][t8 + 4];
            float4 m0 = *(const float4*)&musT[wm * 100 + t8];
            float4 m1 = *(const float4*)&musT[wm * 100 + t8 + 4];
            float4 r0 = *(const float4*)&rgsT[wm * 100 + t8];
            float4 r1 = *(const float4*)&rgsT[wm * 100 + t8 + 4];
            float vv[8];
            vv[0] = ((a0.x * wlc + x0.x * wic + base) - m0.x) * (r0.x * gwc) + gbc;
            vv[1] = ((a0.y * wlc + x0.y * wic + base) - m0.y) * (r0.y * gwc) + gbc;
            vv[2] = ((a0.z * wlc + x0.z * wic + base) - m0.z) * (r0.z * gwc) + gbc;
            vv[3] = ((a0.w * wlc + x0.w * wic + base) - m0.w) * (r0.w * gwc) + gbc;
            vv[4] = ((a1.x * wlc + x1.x * wic + base) - m1.x) * (r1.x * gwc) + gbc;
            vv[5] = ((a1.y * wlc + x1.y * wic + base) - m1.y) * (r1.y * gwc) + gbc;
            vv[6] = ((a1.z * wlc + x1.z * wic + base) - m1.z) * (r1.z * gwc) + gbc;
            vv[7] = ((a1.w * wlc + x1.w * wic + base) - m1.w) * (r1.w * gwc) + gbc;
            union { short8v v; __hip_bfloat162 h2[4]; } o;
            o.h2[0] = __float22bfloat162_rn(make_float2(vv[0], vv[1]));
            o.h2[1] = __float22bfloat162_rn(make_float2(vv[2], vv[3]));
            o.h2[2] = __float22bfloat162_rn(make_float2(vv[4], vv[5]));
            o.h2[3] = __float22bfloat162_rn(make_float2(vv[6], vv[7]));
            *(short8v*)&Hs[c * 104 + t8] = o.v;   // residual copy (wave-private)
#pragma unroll
            for (int mt = 0; mt < 4; ++mt)
                acc1[mt] = __builtin_amdgcn_mfma_f32_16x16x32_bf16(w1f[mt][k0], o.v, acc1[mt], 0, 0, 0);
        }

        // relu + bias -> Hd[c][h] (b64 writes; wave-private rows)
#pragma unroll
        for (int mt = 0; mt < 4; ++mt) {
            __hip_bfloat162 p0 = __float22bfloat162_rn(make_float2(
                fmaxf(acc1[mt][0] + b1q[mt].x, 0.f), fmaxf(acc1[mt][1] + b1q[mt].y, 0.f)));
            __hip_bfloat162 p1 = __float22bfloat162_rn(make_float2(
                fmaxf(acc1[mt][2] + b1q[mt].z, 0.f), fmaxf(acc1[mt][3] + b1q[mt].w, 0.f)));
            union { uint2 u; __hip_bfloat162 h2[2]; } w;
            w.h2[0] = p0; w.h2[1] = p1;
            *(uint2*)&Hd[c * 104 + 16 * mt + 4 * g4] = w.u;
        }

        // GEMM2: D[c][t] = Hd-row x W2frag
        f32x4 acc2[6] = {{0.f, 0.f, 0.f, 0.f}, {0.f, 0.f, 0.f, 0.f},
                         {0.f, 0.f, 0.f, 0.f}, {0.f, 0.f, 0.f, 0.f},
                         {0.f, 0.f, 0.f, 0.f}, {0.f, 0.f, 0.f, 0.f}};
#pragma unroll
        for (int ks = 0; ks < 2; ++ks) {
            short8v af = *(const short8v*)&Hd[c * 104 + 32 * ks + 8 * g4];
#pragma unroll
            for (int mt2 = 0; mt2 < 6; ++mt2)
                acc2[mt2] = __builtin_amdgcn_mfma_f32_16x16x32_bf16(af, w2f[mt2][ks], acc2[mt2], 0, 0, 0);
        }

        // epilogue: residual + b2 -> silu -> *w_out -> reduce over c
#pragma unroll
        for (int mt2 = 0; mt2 < 6; ++mt2) {
            int tv = 16 * mt2 + lq;
            float pm = 0.f;
#pragma unroll
            for (int r = 0; r < 4; ++r) {
                float res = bf2f(Hs[(16 * wm + 4 * g4 + r) * 104 + tv]);
                float z = res + acc2[mt2][r] + b2q[mt2];
                float sg = __builtin_amdgcn_rcpf(1.f + __expf(-z));
                pm += z * sg * wo4[r];
            }
            pm += __shfl_xor(pm, 16);
            pm += __shfl_xor(pm, 32);
            if (g4 == 0) redp[nn][tv][wm] = pm;
        }
    }
    __syncthreads();

    // ---- final: cross-wave reduce + float4 store [t][n0..n0+3] ----
    if (tid < 96) {
        float bo = b_out[0];
        float4 y;
        float* py = (float*)&y;
#pragma unroll
        for (int nn = 0; nn < 4; ++nn) {
            float4 v = *(const float4*)&redp[nn][tid][0];
            py[nn] = v.x + v.y + v.z + v.w + bo;
        }
        *(float4*)&out[(b * T_ + tid) * N_ + n0] = y;
    }
}

// ---------------------------------------------------------------------------
extern "C" void kernel_launch(void* const* d_in, const int* in_sizes, int n_in,
                              void* d_out, int out_size, void* d_ws, size_t ws_size,
                              hipStream_t stream) {
    const float* x     = (const float*)d_in[0];
    const float* adj   = (const float*)d_in[1];
    const int*   ntype = (const int*)d_in[2];
    const float* w_in  = (const float*)d_in[3];
    const float* b_in  = (const float*)d_in[4];
    const float* wpool = (const float*)d_in[5];
    const float* emb   = (const float*)d_in[6];
    const float* gn_w  = (const float*)d_in[7];
    const float* gn_b  = (const float*)d_in[8];
    const float* w1    = (const float*)d_in[9];
    const float* b1    = (const float*)d_in[10];
    const float* w2    = (const float*)d_in[11];
    const float* b2    = (const float*)d_in[12];
    const float* w_out = (const float*)d_in[13];
    const float* b_out = (const float*)d_in[14];
    float* out = (float*)d_out;
    float* ws = (float*)d_ws;

    float* wp1  = ws;             // 512
    float* wpb  = ws + 512;       // 512
    float* rsv  = ws + 1024;      // 1024
    float* WT   = ws + 2048;      // 192
    float* BTb  = ws + 2240;      // 192
    float* TAB  = ws + 2432;      // 108
    float* GG   = ws + 2540;      // 20
    float* muT  = ws + 2560;      // 3072
    float* rgT  = ws + 5632;      // 3072
    ushort* wfrag1 = (ushort*)(ws + 8704);   // 6144 ushorts
    ushort* wfrag2 = (ushort*)(ws + 11776);  // 6144 ushorts
    float* axb  = ws + 14848;     // 786432
    float* axTb = ws + 14848 + 786432;       // 786432
    float* xTb  = ws + 14848 + 2 * 786432;   // 786432

    k_setup<<<dim3(1219), dim3(256), 0, stream>>>(wpool, w_in, b_in, adj, w1, w2, x,
                                                  wp1, wpb, rsv, wfrag1, wfrag2, xTb);
    k_tab<<<dim3(1), dim3(256), 0, stream>>>(wp1, wpb, emb, w_in, b_in,
                                             WT, BTb, TAB, GG);
    k_ax<<<dim3(32, 24), dim3(256), 0, stream>>>(x, adj, axb, axTb);
    k_gn<<<dim3(768), dim3(256), 0, stream>>>(x, axb, rsv, ntype, TAB, GG, muT, rgT);
    k_main<<<dim3(256, 8), dim3(256), 0, stream>>>(xTb, axTb, rsv, ntype, WT, BTb,
                                                   muT, rgT, w_in, b_in, gn_w, gn_b,
                                                   wfrag1, wfrag2, b1, b2,
                                                   w_out, b_out, out);
}

// Round 8
// 81.930 us; speedup vs baseline: 2.2577x; 2.2577x over previous
//
#include <hip/hip_runtime.h>
#include <hip/hip_bf16.h>
#include <math.h>

#define B_   8
#define T_   96
#define N_   1024
#define C_   64
#define H_   64
#define BT_  768
#define EMB_ 8

typedef __attribute__((ext_vector_type(8))) short short8v;
typedef __attribute__((ext_vector_type(4))) float f32x4;

__device__ __forceinline__ ushort f2bf(float f) {   // RNE bf16
    unsigned int u = __float_as_uint(f);
    unsigned int r = (u + 0x7fffu + ((u >> 16) & 1u)) >> 16;
    return (ushort)r;
}
__device__ __forceinline__ float bf2f(ushort h) {
    return __uint_as_float(((unsigned int)h) << 16);
}

// ---------------------------------------------------------------------------
// k_setup: bid 0 = wp1/wpb; bid 1 = w1 -> MFMA-A-frag bf16; bid 2 = w2 ->
// MFMA-B-frag bf16; bids 3..194 = x transpose tiles (64x64) -> xT[n][bt].
// (adj row sums moved into k_ax)
// ---------------------------------------------------------------------------
__global__ __launch_bounds__(256) void k_setup(const float* __restrict__ wpool,
                                               const float* __restrict__ w_in,
                                               const float* __restrict__ b_in,
                                               const float* __restrict__ w1,
                                               const float* __restrict__ w2,
                                               const float* __restrict__ x,
                                               float* __restrict__ wp1,
                                               float* __restrict__ wpb,
                                               ushort* __restrict__ wfrag1,
                                               ushort* __restrict__ wfrag2,
                                               float* __restrict__ xT) {
    int bid = blockIdx.x;
    int tid = threadIdx.x;
    if (bid == 0) {
        for (int e = tid; e < EMB_ * C_; e += 256) {
            int d = e >> 6, c = e & 63;
            float s1 = 0.f, s2 = 0.f;
            for (int i = 0; i < C_; ++i) {
                float w = wpool[(d * C_ + i) * C_ + c];
                s1 += w_in[i] * w;
                s2 += b_in[i] * w;
            }
            wp1[e] = s1;
            wpb[e] = s2;
        }
    } else if (bid == 1) {
        for (int e = tid; e < 6144; e += 256) {
            int j = e & 7, lane = (e >> 3) & 63, frag = e >> 9;
            int mt = frag / 3, k0 = frag - 3 * mt;
            int h = 16 * mt + (lane & 15);
            int t = 32 * k0 + 8 * (lane >> 4) + j;
            wfrag1[e] = f2bf(w1[h * T_ + t]);
        }
    } else if (bid == 2) {
        for (int e = tid; e < 6144; e += 256) {
            int j = e & 7, lane = (e >> 3) & 63, frag = e >> 9;
            int mt2 = frag >> 1, ks = frag & 1;
            int t = 16 * mt2 + (lane & 15);
            int h = 32 * ks + 8 * (lane >> 4) + j;
            wfrag2[e] = f2bf(w2[t * H_ + h]);
        }
    } else {
        // transpose x[768][1024] -> xT[1024][768], 64x64 tiles
        __shared__ float tile[64][65];
        int tnum = bid - 3;             // 0..191
        int ti = tnum >> 4;             // 0..11  (bt tiles)
        int tj = tnum & 15;             // 0..15  (n tiles)
#pragma unroll
        for (int k = 0; k < 16; ++k) {
            int idx = tid + 256 * k;    // 0..4095
            int r = idx >> 6, cq = idx & 63;
            tile[r][cq] = x[(ti * 64 + r) * N_ + tj * 64 + cq];
        }
        __syncthreads();
#pragma unroll
        for (int k = 0; k < 16; ++k) {
            int idx = tid + 256 * k;
            int r = idx >> 6, cq = idx & 63;
            xT[(tj * 64 + r) * BT_ + ti * 64 + cq] = tile[cq][r];
        }
    }
}

// ---------------------------------------------------------------------------
// k_tab: 1 block. waves 0..2 (ty): WT/BT[3][64] + per-(ty,group) sums TAB[3][4][9]
// wave 3: GG[4][5]
// ---------------------------------------------------------------------------
__global__ __launch_bounds__(256) void k_tab(const float* __restrict__ wp1,
                                             const float* __restrict__ wpb,
                                             const float* __restrict__ emb,
                                             const float* __restrict__ w_in,
                                             const float* __restrict__ b_in,
                                             float* __restrict__ WT,
                                             float* __restrict__ BTb,
                                             float* __restrict__ TAB,
                                             float* __restrict__ GG) {
    int tid = threadIdx.x;
    int wave = tid >> 6, lane = tid & 63;
    int lq = lane & 15, g = lane >> 4;
    if (wave < 3) {
        int ty = wave, c = lane;
        float w = 0.f, bb = 0.f;
#pragma unroll
        for (int d = 0; d < EMB_; ++d) {
            float ev = emb[ty * EMB_ + d];
            w += ev * wp1[d * C_ + c];
            bb += ev * wpb[d * C_ + c];
        }
        WT[ty * C_ + c] = w;
        BTb[ty * C_ + c] = bb;
        float wi = w_in[c], bi = b_in[c];
        float vals[9] = {w, bb, w * w, bb * bb, w * wi, w * bi, wi * bb, bb * bi, w * bb};
#pragma unroll
        for (int q = 0; q < 9; ++q) {
            vals[q] += __shfl_xor(vals[q], 1);
            vals[q] += __shfl_xor(vals[q], 2);
            vals[q] += __shfl_xor(vals[q], 4);
            vals[q] += __shfl_xor(vals[q], 8);
        }
        if (lq == 0) {
#pragma unroll
            for (int q = 0; q < 9; ++q) TAB[(ty * 4 + g) * 9 + q] = vals[q];
        }
    } else {
        int c = lane;
        float wi = w_in[c], bi = b_in[c];
        float v5[5] = {wi, bi, wi * wi, bi * bi, wi * bi};
#pragma unroll
        for (int q = 0; q < 5; ++q) {
            v5[q] += __shfl_xor(v5[q], 1);
            v5[q] += __shfl_xor(v5[q], 2);
            v5[q] += __shfl_xor(v5[q], 4);
            v5[q] += __shfl_xor(v5[q], 8);
        }
        if (lq == 0) {
#pragma unroll
            for (int q = 0; q < 5; ++q) GG[g * 5 + q] = v5[q];
        }
    }
}

// ---------------------------------------------------------------------------
// k_ax (bf16 MFMA): ax[bt][n] + axT[n][bt]; by==0 blocks also compute
// rs[n] = sum_m adj[n][m] from the fp32 staging values.
// ---------------------------------------------------------------------------
__global__ __launch_bounds__(256, 4) void k_ax(const float* __restrict__ x,
                                               const float* __restrict__ adj,
                                               float* __restrict__ axo,
                                               float* __restrict__ axT,
                                               float* __restrict__ rs) {
    __shared__ ushort Xs[32 * 64];
    __shared__ ushort As[32 * 64];
    const int tid = threadIdx.x;
    const int wave = tid >> 6, lane = tid & 63;
    const int lq = lane & 15, g4 = lane >> 4;
    const int n0 = blockIdx.x * 32, m0 = blockIdx.y * 32;
    const int mi = wave >> 1, ni = wave & 1;
    const int sr = tid >> 3, sq = tid & 7;
    const int sqx = sq ^ (sr & 7);
    const int ra = 16 * mi + lq, rb = 16 * ni + lq;

    f32x4 acc = {0.f, 0.f, 0.f, 0.f};
    float rsacc = 0.f;

    for (int k0 = 0; k0 < N_; k0 += 64) {
        __syncthreads();
        {
            const float* px = x + (m0 + sr) * N_ + k0 + sq * 8;
            float4 xa = *(const float4*)px;
            float4 xb = *(const float4*)(px + 4);
            union { short8v v; __hip_bfloat162 h[4]; } o;
            o.h[0] = __float22bfloat162_rn(make_float2(xa.x, xa.y));
            o.h[1] = __float22bfloat162_rn(make_float2(xa.z, xa.w));
            o.h[2] = __float22bfloat162_rn(make_float2(xb.x, xb.y));
            o.h[3] = __float22bfloat162_rn(make_float2(xb.z, xb.w));
            *(short8v*)&Xs[sr * 64 + sqx * 8] = o.v;

            const float* pa = adj + (n0 + sr) * N_ + k0 + sq * 8;
            float4 aa = *(const float4*)pa;
            float4 ab = *(const float4*)(pa + 4);
            if (m0 == 0)
                rsacc += aa.x + aa.y + aa.z + aa.w + ab.x + ab.y + ab.z + ab.w;
            o.h[0] = __float22bfloat162_rn(make_float2(aa.x, aa.y));
            o.h[1] = __float22bfloat162_rn(make_float2(aa.z, aa.w));
            o.h[2] = __float22bfloat162_rn(make_float2(ab.x, ab.y));
            o.h[3] = __float22bfloat162_rn(make_float2(ab.z, ab.w));
            *(short8v*)&As[sr * 64 + sqx * 8] = o.v;
        }
        __syncthreads();
#pragma unroll
        for (int ks = 0; ks < 2; ++ks) {
            short8v a = *(const short8v*)&Xs[ra * 64 + ((4 * ks + g4) ^ (ra & 7)) * 8];
            short8v bb = *(const short8v*)&As[rb * 64 + ((4 * ks + g4) ^ (rb & 7)) * 8];
            acc = __builtin_amdgcn_mfma_f32_16x16x32_bf16(a, bb, acc, 0, 0, 0);
        }
    }
    if (m0 == 0) {
        rsacc += __shfl_xor(rsacc, 1);
        rsacc += __shfl_xor(rsacc, 2);
        rsacc += __shfl_xor(rsacc, 4);
        if (sq == 0) rs[n0 + sr] = rsacc;
    }
#pragma unroll
    for (int r = 0; r < 4; ++r)
        axo[(m0 + 16 * mi + 4 * g4 + r) * N_ + n0 + 16 * ni + lq] = acc[r];
    float4 tv = make_float4(acc[0], acc[1], acc[2], acc[3]);
    *(float4*)&axT[(n0 + 16 * ni + lq) * BT_ + m0 + 16 * mi + 4 * g4] = tv;
}

// ---------------------------------------------------------------------------
// k_gn v2: per bt, per-type feature sums -> mu/rsig via TAB/GG contraction.
// ---------------------------------------------------------------------------
__global__ __launch_bounds__(256) void k_gn(const float* __restrict__ x,
                                            const float* __restrict__ ax,
                                            const float* __restrict__ rs,
                                            const int* __restrict__ ntype,
                                            const float* __restrict__ TAB,
                                            const float* __restrict__ GG,
                                            float* __restrict__ muT,
                                            float* __restrict__ rgT) {
    int bt = blockIdx.x;
    int tid = threadIdx.x;
    const float* axr = ax + bt * N_;
    const float* xr = x + bt * N_;
    float S[23];
#pragma unroll
    for (int q = 0; q < 23; ++q) S[q] = 0.f;
#pragma unroll
    for (int i = 0; i < 4; ++i) {
        int n = tid + 256 * i;
        float a = axr[n], xv = xr[n], r = rs[n];
        int ty = ntype[n];
        float e0 = (ty == 0) ? 1.f : 0.f;
        float e1 = (ty == 1) ? 1.f : 0.f;
        float e2 = (ty == 2) ? 1.f : 0.f;
        float a2 = a * a, axp = a * xv, ar = a * r, xrr = xv * r, r2 = r * r;
        S[0] += e0 * a;   S[1] += e1 * a;   S[2] += e2 * a;
        S[3] += e0 * r;   S[4] += e1 * r;   S[5] += e2 * r;
        S[6] += e0 * a2;  S[7] += e1 * a2;  S[8] += e2 * a2;
        S[9] += e0 * r2;  S[10] += e1 * r2; S[11] += e2 * r2;
        S[12] += e0 * axp; S[13] += e1 * axp; S[14] += e2 * axp;
        S[15] += e0 * ar; S[16] += e1 * ar; S[17] += e2 * ar;
        S[18] += e0 * xrr; S[19] += e1 * xrr; S[20] += e2 * xrr;
        S[21] += xv;      S[22] += xv * xv;
    }
#pragma unroll
    for (int q = 0; q < 23; ++q) {
#pragma unroll
        for (int off = 32; off; off >>= 1) S[q] += __shfl_down(S[q], off);
    }
    __shared__ float wred[4][23];
    __shared__ float tot[23];
    int wave = tid >> 6, lane = tid & 63;
    if (lane == 0) {
#pragma unroll
        for (int q = 0; q < 23; ++q) wred[wave][q] = S[q];
    }
    __syncthreads();
    if (tid < 23) tot[tid] = wred[0][tid] + wred[1][tid] + wred[2][tid] + wred[3][tid];
    __syncthreads();
    if (tid < 4) {
        int g = tid;
        float M = 0.f, Q = 0.f;
#pragma unroll
        for (int ty = 0; ty < 3; ++ty) {
            const float* tb = TAB + (ty * 4 + g) * 9;
            float A1v = tot[0 + ty], R1v = tot[3 + ty], A2v = tot[6 + ty];
            float R2v = tot[9 + ty], AXv = tot[12 + ty], ARv = tot[15 + ty];
            float XRv = tot[18 + ty];
            M += tb[0] * A1v + tb[1] * R1v;
            Q += tb[2] * A2v + tb[3] * R2v +
                 2.f * (tb[4] * AXv + tb[5] * A1v + tb[6] * XRv + tb[7] * R1v + tb[8] * ARv);
        }
        float Sx = tot[21], Sx2 = tot[22];
        const float* gg = GG + g * 5;
        M += gg[0] * Sx + 1024.f * gg[1];
        Q += gg[2] * Sx2 + 2.f * gg[4] * Sx + 1024.f * gg[3];
        const float inv = 1.f / 16384.f;
        float m = M * inv;
        float v = Q * inv - m * m;
        int b = bt / T_, t = bt - b * T_;
        muT[(b * 4 + g) * T_ + t] = m;
        rgT[(b * 4 + g) * T_ + t] = rsqrtf(v + 1e-5f);
    }
}

// ---------------------------------------------------------------------------
// k_main v6: 4 nodes per block, grid (256, 8), 256 threads. Only w1f (48 VGPR)
// resident; w2f/b1/b2/w_out re-loaded per n via opaque pointers (L1-hot,
// defeats LICM hoist -> no spill). No barriers in n-loop.
// ---------------------------------------------------------------------------
__global__ __launch_bounds__(256, 4) void k_main(const float* __restrict__ xT,
                                                 const float* __restrict__ axT,
                                                 const float* __restrict__ rs,
                                                 const int* __restrict__ ntype,
                                                 const float* __restrict__ WT,
                                                 const float* __restrict__ BTb,
                                                 const float* __restrict__ muT,
                                                 const float* __restrict__ rgT,
                                                 const float* __restrict__ w_in,
                                                 const float* __restrict__ b_in,
                                                 const float* __restrict__ gn_w,
                                                 const float* __restrict__ gn_b,
                                                 const ushort* __restrict__ wfrag1,
                                                 const ushort* __restrict__ wfrag2,
                                                 const float* __restrict__ b1,
                                                 const float* __restrict__ b2,
                                                 const float* __restrict__ w_out,
                                                 const float* __restrict__ b_out,
                                                 float* __restrict__ out) {
    __shared__ ushort Hs[64 * 104];
    __shared__ ushort Hd[64 * 104];
    __shared__ float axs[4][96], xs[4][96];
    __shared__ float musT[4 * 100], rgsT[4 * 100];
    __shared__ float redp[4][96][4];

    const int tid = threadIdx.x;
    const int n0 = blockIdx.x * 4;
    const int b = blockIdx.y;
    const int wm = tid >> 6;
    const int lane = tid & 63;
    const int lq = lane & 15;
    const int g4 = lane >> 4;

    // ---- w1f only -> VGPRs (12 x b128 = 48 VGPRs) ----
    short8v w1f[4][3];
#pragma unroll
    for (int mt = 0; mt < 4; ++mt)
#pragma unroll
        for (int k0 = 0; k0 < 3; ++k0)
            w1f[mt][k0] = *(const short8v*)(wfrag1 + (((mt * 3 + k0) << 6) + lane) * 8);

    // ---- coalesced staging ----
    for (int j = tid; j < 384; j += 256) {
        int nn = j / 96, t = j - nn * 96;
        axs[nn][t] = axT[(n0 + nn) * BT_ + b * T_ + t];
        xs[nn][t] = xT[(n0 + nn) * BT_ + b * T_ + t];
    }
    for (int j = tid; j < 384; j += 256) {
        int g = j / 96, t = j - 96 * g;
        musT[g * 100 + t] = muT[b * 384 + j];
        rgsT[g * 100 + t] = rgT[b * 384 + j];
    }

    // ---- per-c constants ----
    const int c = 16 * wm + lq;
    const float wic = w_in[c], bic = b_in[c];
    const float gwc = gn_w[c], gbc = gn_b[c];
    const float wlcA[3] = {WT[c], WT[64 + c], WT[128 + c]};
    const float blcA[3] = {BTb[c], BTb[64 + c], BTb[128 + c]};
    __syncthreads();

    // opaque base pointers (re-loaded per n; asm defeats LICM/CSE -> no spill)
    const ushort* wf2p = wfrag2;
    const float* b1p = b1;
    const float* b2p = b2;
    const float* wop = w_out;

    // ================= n-loop (no internal barriers) =================
#pragma unroll 1
    for (int nn = 0; nn < 4; ++nn) {
        asm volatile("" : "+s"(wf2p), "+s"(b1p), "+s"(b2p), "+s"(wop));
        const int n = n0 + nn;
        const int ty = ntype[n];
        const float wlc = (ty == 0) ? wlcA[0] : (ty == 1) ? wlcA[1] : wlcA[2];
        const float blc = (ty == 0) ? blcA[0] : (ty == 1) ? blcA[1] : blcA[2];
        const float base = rs[n] * blc + bic;

        f32x4 acc1[4] = {{0.f, 0.f, 0.f, 0.f}, {0.f, 0.f, 0.f, 0.f},
                         {0.f, 0.f, 0.f, 0.f}, {0.f, 0.f, 0.f, 0.f}};
#pragma unroll
        for (int k0 = 0; k0 < 3; ++k0) {
            int t8 = 32 * k0 + 8 * g4;
            float4 a0 = *(const float4*)&axs[nn][t8];
            float4 a1 = *(const float4*)&axs[nn][t8 + 4];
            float4 x0 = *(const float4*)&xs[nn][t8];
            float4 x1 = *(const float4*)&xs[nn][t8 + 4];
            float4 m0 = *(const float4*)&musT[wm * 100 + t8];
            float4 m1 = *(const float4*)&musT[wm * 100 + t8 + 4];
            float4 r0 = *(const float4*)&rgsT[wm * 100 + t8];
            float4 r1 = *(const float4*)&rgsT[wm * 100 + t8 + 4];
            float vv[8];
            vv[0] = ((a0.x * wlc + x0.x * wic + base) - m0.x) * (r0.x * gwc) + gbc;
            vv[1] = ((a0.y * wlc + x0.y * wic + base) - m0.y) * (r0.y * gwc) + gbc;
            vv[2] = ((a0.z * wlc + x0.z * wic + base) - m0.z) * (r0.z * gwc) + gbc;
            vv[3] = ((a0.w * wlc + x0.w * wic + base) - m0.w) * (r0.w * gwc) + gbc;
            vv[4] = ((a1.x * wlc + x1.x * wic + base) - m1.x) * (r1.x * gwc) + gbc;
            vv[5] = ((a1.y * wlc + x1.y * wic + base) - m1.y) * (r1.y * gwc) + gbc;
            vv[6] = ((a1.z * wlc + x1.z * wic + base) - m1.z) * (r1.z * gwc) + gbc;
            vv[7] = ((a1.w * wlc + x1.w * wic + base) - m1.w) * (r1.w * gwc) + gbc;
            union { short8v v; __hip_bfloat162 h2[4]; } o;
            o.h2[0] = __float22bfloat162_rn(make_float2(vv[0], vv[1]));
            o.h2[1] = __float22bfloat162_rn(make_float2(vv[2], vv[3]));
            o.h2[2] = __float22bfloat162_rn(make_float2(vv[4], vv[5]));
            o.h2[3] = __float22bfloat162_rn(make_float2(vv[6], vv[7]));
            *(short8v*)&Hs[c * 104 + t8] = o.v;   // residual copy (wave-private)
#pragma unroll
            for (int mt = 0; mt < 4; ++mt)
                acc1[mt] = __builtin_amdgcn_mfma_f32_16x16x32_bf16(w1f[mt][k0], o.v, acc1[mt], 0, 0, 0);
        }

        // relu + bias -> Hd[c][h] (b64 writes; wave-private rows)
#pragma unroll
        for (int mt = 0; mt < 4; ++mt) {
            float4 b1v = *(const float4*)(b1p + 16 * mt + 4 * g4);
            __hip_bfloat162 p0 = __float22bfloat162_rn(make_float2(
                fmaxf(acc1[mt][0] + b1v.x, 0.f), fmaxf(acc1[mt][1] + b1v.y, 0.f)));
            __hip_bfloat162 p1 = __float22bfloat162_rn(make_float2(
                fmaxf(acc1[mt][2] + b1v.z, 0.f), fmaxf(acc1[mt][3] + b1v.w, 0.f)));
            union { uint2 u; __hip_bfloat162 h2[2]; } w;
            w.h2[0] = p0; w.h2[1] = p1;
            *(uint2*)&Hd[c * 104 + 16 * mt + 4 * g4] = w.u;
        }

        // GEMM2: D[c][t] = Hd-row x W2frag (frags re-loaded, L1-hot)
        f32x4 acc2[6] = {{0.f, 0.f, 0.f, 0.f}, {0.f, 0.f, 0.f, 0.f},
                         {0.f, 0.f, 0.f, 0.f}, {0.f, 0.f, 0.f, 0.f},
                         {0.f, 0.f, 0.f, 0.f}, {0.f, 0.f, 0.f, 0.f}};
#pragma unroll
        for (int ks = 0; ks < 2; ++ks) {
            short8v af = *(const short8v*)&Hd[c * 104 + 32 * ks + 8 * g4];
#pragma unroll
            for (int mt2 = 0; mt2 < 6; ++mt2) {
                short8v bf = *(const short8v*)(wf2p + (((mt2 * 2 + ks) << 6) + lane) * 8);
                acc2[mt2] = __builtin_amdgcn_mfma_f32_16x16x32_bf16(af, bf, acc2[mt2], 0, 0, 0);
            }
        }

        // epilogue: residual + b2 -> silu -> *w_out -> reduce over c
        float4 wo4 = *(const float4*)(wop + 16 * wm + 4 * g4);
#pragma unroll
        for (int mt2 = 0; mt2 < 6; ++mt2) {
            int tv = 16 * mt2 + lq;
            float bz = b2p[tv];
            float pm = 0.f;
#pragma unroll
            for (int r = 0; r < 4; ++r) {
                float res = bf2f(Hs[(16 * wm + 4 * g4 + r) * 104 + tv]);
                float z = res + acc2[mt2][r] + bz;
                float sg = __builtin_amdgcn_rcpf(1.f + __expf(-z));
                pm += z * sg * wo4[r];
            }
            pm += __shfl_xor(pm, 16);
            pm += __shfl_xor(pm, 32);
            if (g4 == 0) redp[nn][tv][wm] = pm;
        }
    }
    __syncthreads();

    // ---- final: cross-wave reduce + float4 store [t][n0..n0+3] ----
    if (tid < 96) {
        float bo = b_out[0];
        float4 y;
        float* py = (float*)&y;
#pragma unroll
        for (int nn = 0; nn < 4; ++nn) {
            float4 v = *(const float4*)&redp[nn][tid][0];
            py[nn] = v.x + v.y + v.z + v.w + bo;
        }
        *(float4*)&out[(b * T_ + tid) * N_ + n0] = y;
    }
}

// ---------------------------------------------------------------------------
extern "C" void kernel_launch(void* const* d_in, const int* in_sizes, int n_in,
                              void* d_out, int out_size, void* d_ws, size_t ws_size,
                              hipStream_t stream) {
    const float* x     = (const float*)d_in[0];
    const float* adj   = (const float*)d_in[1];
    const int*   ntype = (const int*)d_in[2];
    const float* w_in  = (const float*)d_in[3];
    const float* b_in  = (const float*)d_in[4];
    const float* wpool = (const float*)d_in[5];
    const float* emb   = (const float*)d_in[6];
    const float* gn_w  = (const float*)d_in[7];
    const float* gn_b  = (const float*)d_in[8];
    const float* w1    = (const float*)d_in[9];
    const float* b1    = (const float*)d_in[10];
    const float* w2    = (const float*)d_in[11];
    const float* b2    = (const float*)d_in[12];
    const float* w_out = (const float*)d_in[13];
    const float* b_out = (const float*)d_in[14];
    float* out = (float*)d_out;
    float* ws = (float*)d_ws;

    float* wp1  = ws;             // 512
    float* wpb  = ws + 512;       // 512
    float* rsv  = ws + 1024;      // 1024
    float* WT   = ws + 2048;      // 192
    float* BTb  = ws + 2240;      // 192
    float* TAB  = ws + 2432;      // 108
    float* GG   = ws + 2540;      // 20
    float* muT  = ws + 2560;      // 3072
    float* rgT  = ws + 5632;      // 3072
    ushort* wfrag1 = (ushort*)(ws + 8704);   // 6144 ushorts
    ushort* wfrag2 = (ushort*)(ws + 11776);  // 6144 ushorts
    float* axb  = ws + 14848;     // 786432
    float* axTb = ws + 14848 + 786432;       // 786432
    float* xTb  = ws + 14848 + 2 * 786432;   // 786432

    k_setup<<<dim3(195), dim3(256), 0, stream>>>(wpool, w_in, b_in, w1, w2, x,
                                                 wp1, wpb, wfrag1, wfrag2, xTb);
    k_tab<<<dim3(1), dim3(256), 0, stream>>>(wp1, wpb, emb, w_in, b_in,
                                             WT, BTb, TAB, GG);
    k_ax<<<dim3(32, 24), dim3(256), 0, stream>>>(x, adj, axb, axTb, rsv);
    k_gn<<<dim3(768), dim3(256), 0, stream>>>(x, axb, rsv, ntype, TAB, GG, muT, rgT);
    k_main<<<dim3(256, 8), dim3(256), 0, stream>>>(xTb, axTb, rsv, ntype, WT, BTb,
                                                   muT, rgT, w_in, b_in, gn_w, gn_b,
                                                   wfrag1, wfrag2, b1, b2,
                                                   w_out, b_out, out);
}